// Round 12
// baseline (180.820 us; speedup 1.0000x reference)
//
#include <hip/hip_runtime.h>

// All spike-critical math in f64; part f32 (validated r10/r11, absmax=0).
// This round: 4 kernels -> 2 via split-K "last-block-done" atomics (no coop
// launch). Inner math byte-identical to r11's passing build; only the sync
// structure changed.
//
// Workspace layout (bytes):
//  partf   : f32[32][416][64] = 3,407,872  (fc1 K-split partials, lane-n)
//  smaskT2 : u64[100][416]    =   332,800  (layer-1 spike masks, f-contig per t)
//  a2s     : f64[10][100][64] =   512,000
//  ctr     : u32[64]          =       256  (zeroed each launch by memset node;
//                                           [0..25]=og counters, [32..41]=o)
#define WS_PART   0
#define WS_SMASK  3407872
#define WS_A2     (WS_SMASK + 332800)
#define WS_CTR    (WS_A2 + 512000)

#define D_E1   2.71828182845904523536   // e
#define D_EINV 0.36787944117144232160   // e^-1
#define D_G10  0.90483741803595957316   // e^-0.1
#define D_E10  0.27182818284590452354   // e/10

// ---------------------------------------------------------------------------
// Kernel A: fc1 GEMM + (last block per o-group) layer-1 spike sim.
// Grid 832 = 32 K-splits x 26 o-groups; block 256. GEMM phase identical to
// r11. Then: syncthreads (drains all block stores), thread0 threadfence
// (L2 writeback) + atomicAdd(ctr[og]); the 32nd block threadfence-acquires
// and runs sim1 for its o-group's 16 f's (4 waves x 4 f), overlapping other
// groups' GEMM blocks.
// ---------------------------------------------------------------------------
__global__ __launch_bounds__(256) void k_gemm_sim1(
    const float* __restrict__ flat, const float* __restrict__ w1,
    float* __restrict__ partf, unsigned* __restrict__ ctr,
    unsigned long long* __restrict__ smaskT2)
{
    __shared__ float tile[64 * 98];   // A[n][k0..k0+95]
    __shared__ int lastFlag;
    const int b   = blockIdx.x;       // 0..831
    const int s   = b & 31;           // K-split
    const int og  = b >> 5;           // 0..25
    const int k0  = s * 96;
    const int tid = threadIdx.x;

    {   // stage A: thread (row=tid>>2, q=tid&3) copies 6 float4 coalesced
        const int row = tid >> 2, q = tid & 3;
        const float4* A4 = (const float4*)flat;   // row stride 768 float4
        const int gbase = row * 768 + s * 24 + q * 6;
        float* dst = &tile[row * 98 + q * 24];
#pragma unroll
        for (int i = 0; i < 6; ++i) {
            float4 v = A4[gbase + i];
            dst[i * 4 + 0] = v.x; dst[i * 4 + 1] = v.y;
            dst[i * 4 + 2] = v.z; dst[i * 4 + 3] = v.w;
        }
    }
    __syncthreads();

    const int w  = __builtin_amdgcn_readfirstlane(tid >> 6);   // wave 0..3
    const int o0 = og * 16 + w * 4;                            // 0..412
    const int n  = tid & 63;

    {
        double acc[4];
#pragma unroll
        for (int o = 0; o < 4; ++o) acc[o] = 0.0;

        const float* bp[4];
        bool valid[4];
#pragma unroll
        for (int o = 0; o < 4; ++o) {
            const int row = o0 + o;
            valid[o] = (row < 410);
            bp[o] = w1 + (size_t)(valid[o] ? row : 409) * 3072 + k0;
        }

#pragma unroll 4
        for (int kk = 0; kk < 96; kk += 8) {
            double ad[8];
            {
                float2 f0 = *(const float2*)&tile[n * 98 + kk + 0];
                float2 f1 = *(const float2*)&tile[n * 98 + kk + 2];
                float2 f2 = *(const float2*)&tile[n * 98 + kk + 4];
                float2 f3 = *(const float2*)&tile[n * 98 + kk + 6];
                ad[0] = (double)f0.x; ad[1] = (double)f0.y;
                ad[2] = (double)f1.x; ad[3] = (double)f1.y;
                ad[4] = (double)f2.x; ad[5] = (double)f2.y;
                ad[6] = (double)f3.x; ad[7] = (double)f3.y;
            }
#pragma unroll
            for (int o = 0; o < 4; ++o) {
                float4 ba = *(const float4*)(bp[o] + kk);      // wave-uniform
                float4 bb = *(const float4*)(bp[o] + kk + 4);
                acc[o] = fma(ad[0], (double)ba.x, acc[o]);
                acc[o] = fma(ad[1], (double)ba.y, acc[o]);
                acc[o] = fma(ad[2], (double)ba.z, acc[o]);
                acc[o] = fma(ad[3], (double)ba.w, acc[o]);
                acc[o] = fma(ad[4], (double)bb.x, acc[o]);
                acc[o] = fma(ad[5], (double)bb.y, acc[o]);
                acc[o] = fma(ad[6], (double)bb.z, acc[o]);
                acc[o] = fma(ad[7], (double)bb.w, acc[o]);
            }
        }

        float* prow = partf + (size_t)s * (416 * 64);
#pragma unroll
        for (int o = 0; o < 4; ++o)
            prow[(size_t)(o0 + o) * 64 + n] = valid[o] ? (float)acc[o] : 0.0f;
    }

    // ---- last-block detection for this o-group ----
    __syncthreads();                       // all block stores issued & drained
    if (tid == 0) {
        __threadfence();                   // release: writeback to L3
        unsigned old = atomicAdd(&ctr[og], 1u);
        lastFlag = (old == 31u);
    }
    __syncthreads();
    if (!lastFlag) return;
    __threadfence();                       // acquire: invalidate stale lines

    // ---- sim1 for this o-group's 16 f's (4 waves x 4 f), math == r11 ----
    const bool l0 = (n == 0);
#pragma unroll 1
    for (int ff = 0; ff < 4; ++ff) {
        const int f = og * 16 + w * 4 + ff;
        double a1 = 0.0;
#pragma unroll
        for (int s2 = 0; s2 < 32; ++s2)
            a1 += (double)partf[((size_t)s2 * 416 + f) * 64 + n];

        double Et = D_E1, cs = 0.0, RA = 0.0, RB = 0.0;
#pragma unroll 4
        for (int t = 0; t < 100; ++t) {
            cs = fma(0.1 * (double)t, Et, cs);     // csum[t]
            double m = fma(a1, cs, RA);            // u + refractory
            bool sp = (m >= 10.0);
            unsigned long long bl = __ballot(sp);
            if (l0) smaskT2[(size_t)t * 416 + f] = bl;
            double t1 = (RA + RB) * D_EINV;
            double t2 = RB * D_EINV;
            RA = sp ? t1 - 20.0 : t1;
            RB = sp ? t2 - 20.0 : t2;
            Et *= D_G10;
        }
    }
}

// ---------------------------------------------------------------------------
// Kernel B: fc2 + (last block per o) fused psp2/layer-2 scan.
// Grid 250 = 10 o x 25 t-quads; block 256, wave per t. fc2 phase identical to
// r11 (20-batched uniform loads, unroll 2, c0/c1 parity chains). Last block
// per o runs the r11 tail scan (25-deep prefetch) on wave 0.
// ---------------------------------------------------------------------------
__global__ __launch_bounds__(256) void k_fc2_tail(
    const unsigned long long* __restrict__ smaskT2, const float* __restrict__ w2,
    double* __restrict__ a2s, unsigned* __restrict__ ctr,
    float* __restrict__ out)
{
    __shared__ int lastFlag;
    const int blk = blockIdx.x;                 // 0..249
    const int o   = blk / 25;
    const int tq  = blk - o * 25;
    const int wi  = threadIdx.x >> 6;
    const int t   = __builtin_amdgcn_readfirstlane(tq * 4 + wi);
    const int n   = threadIdx.x & 63;

    {
        const unsigned long long* mrow = smaskT2 + (size_t)t * 416;
        const float* wrow = w2 + o * 410;

        double c0 = 0.0, c1 = 0.0;
#pragma unroll 2
        for (int f0 = 0; f0 < 400; f0 += 20) {
            unsigned long long m[20];
            float wv[20];
#pragma unroll
            for (int i = 0; i < 20; ++i) { m[i] = mrow[f0 + i]; wv[i] = wrow[f0 + i]; }
#pragma unroll
            for (int i = 0; i < 20; ++i) {
                double bit = (double)((unsigned)((m[i] >> n) & 1ull));
                double wd  = (double)wv[i];
                if (i & 1) c1 = fma(bit, wd, c1);
                else       c0 = fma(bit, wd, c0);
            }
        }
        {   // tail 10 (400..409)
            unsigned long long m[10];
            float wv[10];
#pragma unroll
            for (int i = 0; i < 10; ++i) { m[i] = mrow[400 + i]; wv[i] = wrow[400 + i]; }
#pragma unroll
            for (int i = 0; i < 10; ++i) {
                double bit = (double)((unsigned)((m[i] >> n) & 1ull));
                double wd  = (double)wv[i];
                if (i & 1) c1 = fma(bit, wd, c1);
                else       c0 = fma(bit, wd, c0);
            }
        }
        a2s[((size_t)o * 100 + t) * 64 + n] = c0 + c1;
    }

    // ---- last-block detection for this o ----
    __syncthreads();
    if (threadIdx.x == 0) {
        __threadfence();                   // release
        unsigned old = atomicAdd(&ctr[32 + o], 1u);
        lastFlag = (old == 24u);
    }
    __syncthreads();
    if (!lastFlag) return;
    __threadfence();                       // acquire
    if (threadIdx.x >= 64) return;         // wave 0 runs the o-scan

    // ---- tail scan for this o (math == r11: 25-deep prefetch, 4 chunks) ----
    const double* ap = a2s + (size_t)o * 6400 + n;
    float* orow = out + (size_t)n * 1000 + o * 100;

    double PA = 0.0, PB = 0.0, RA = 0.0, RB = 0.0;
#pragma unroll 1
    for (int tb = 0; tb < 4; ++tb) {
        double a[25];
#pragma unroll
        for (int i = 0; i < 25; ++i) a[i] = ap[(size_t)(tb * 25 + i) * 64];
#pragma unroll
        for (int i = 0; i < 25; ++i) {
            PB = fma(D_E10, a[i], PB);     // ingest a2[t]
            double m = PA + RA;            // u2[t] + refractory
            bool sp = (m >= 10.0);
            orow[tb * 25 + i] = sp ? 1.0f : 0.0f;
            double p1 = (PA + PB) * D_G10;
            PB *= D_G10;
            PA = p1;
            double r1 = (RA + RB) * D_EINV;
            double r2 = RB * D_EINV;
            RA = sp ? r1 - 20.0 : r1;
            RB = sp ? r2 - 20.0 : r2;
        }
    }
}

// ---------------------------------------------------------------------------
extern "C" void kernel_launch(void* const* d_in, const int* in_sizes, int n_in,
                              void* d_out, int out_size, void* d_ws, size_t ws_size,
                              hipStream_t stream) {
    const float* input = (const float*)d_in[0];  // (64,3,32,32) == flat (64,3072)
    const float* w1    = (const float*)d_in[1];  // (410,3072)
    const float* w2    = (const float*)d_in[2];  // (10,410)
    float* out = (float*)d_out;                  // (64,10,100) f32

    char* ws = (char*)d_ws;
    float* partf = (float*)(ws + WS_PART);
    unsigned long long* smaskT2 = (unsigned long long*)(ws + WS_SMASK);
    double* a2s  = (double*)(ws + WS_A2);
    unsigned* ctr = (unsigned*)(ws + WS_CTR);

    hipMemsetAsync(ctr, 0, 256, stream);   // zero the last-block counters
    k_gemm_sim1<<<832, 256, 0, stream>>>(input, w1, partf, ctr, smaskT2);
    k_fc2_tail <<<250, 256, 0, stream>>>(smaskT2, w2, a2s, ctr, out);
}